// Round 10
// baseline (165.699 us; speedup 1.0000x reference)
//
#include <hip/hip_runtime.h>

#define HW 16384
#define C 128

typedef __attribute__((ext_vector_type(8))) short short8;
typedef __attribute__((ext_vector_type(4))) float f32x4;
typedef __attribute__((ext_vector_type(2))) float f32x2;
typedef __attribute__((ext_vector_type(16))) int v16i;

__device__ __forceinline__ unsigned short f2bf(float f) {
  union { float f; unsigned u; } v; v.f = f;
  return (unsigned short)((v.u + 0x7fffu + ((v.u >> 16) & 1u)) >> 16);
}
#if __has_builtin(__builtin_amdgcn_cvt_pk_bf16_f32)
typedef __attribute__((ext_vector_type(2))) __bf16 bf16x2;
__device__ __forceinline__ unsigned pk2(float a, float b) {   // HW RNE pack
  union { bf16x2 v; unsigned u; } cv;
  cv.v = __builtin_amdgcn_cvt_pk_bf16_f32(a, b);
  return cv.u;
}
#else
__device__ __forceinline__ unsigned pk2(float a, float b) {   // SW RNE pack
  return (unsigned)f2bf(a) | ((unsigned)f2bf(b) << 16);
}
#endif
__device__ __forceinline__ unsigned short f2bf1(float a) {
  return (unsigned short)(pk2(a, a) & 0xffffu);
}
__device__ __forceinline__ float bflo(unsigned w) {
  union { unsigned u; float f; } v; v.u = w << 16; return v.f;
}
__device__ __forceinline__ float bfhi(unsigned w) {
  union { unsigned u; float f; } v; v.u = w & 0xffff0000u; return v.f;
}
__device__ __forceinline__ float asf(int u) {
  union { int u; float f; } v; v.u = u; return v.f;
}

// ---------------- Kernel 0: precompute Mt = C^-0.5 * Wk^T Wq, P = Wproj @ Wv,
// both stored bf16 with the fragment XOR swizzle pre-applied, plus pw/pi.
__global__ __launch_bounds__(128) void k_prep(const float* __restrict__ w_qkv,
                                              const float* __restrict__ w_proj,
                                              const float* __restrict__ delta,
                                              unsigned short* __restrict__ Mt,
                                              unsigned short* __restrict__ Pm,
                                              float* __restrict__ pw,
                                              int* __restrict__ pi) {
  const int bid = blockIdx.x;
  const int t = threadIdx.x;
  if (bid == 256) {
    if (t < 8) {
      float s0 = tanhf(delta[t * 2 + 0]) * 4.0f;  // col shift (x)
      float s1 = tanhf(delta[t * 2 + 1]) * 4.0f;  // row shift (y)
      float f0 = floorf(s0), f1 = floorf(s1);
      pi[2 * t + 0] = (int)f0;
      pi[2 * t + 1] = (int)f1;
      float fx = s0 - f0, fy = s1 - f1;
      pw[4 * t + 0] = (1.0f - fx) * (1.0f - fy);
      pw[4 * t + 1] = fx * (1.0f - fy);
      pw[4 * t + 2] = (1.0f - fx) * fy;
      pw[4 * t + 3] = fx * fy;
    }
    return;
  }
  const int R = bid & 127;
  float acc = 0.0f;
  if (bid < 128) {                         // Mt row R
    const float* wq = w_qkv;               // Wq[j][c]
    const float* wk = w_qkv + 128 * 128;   // Wk[j][o]
    #pragma unroll 16
    for (int j = 0; j < 128; ++j)
      acc += wk[j * 128 + R] * wq[j * 128 + t];   // wk: scalar, wq: coalesced
    acc *= 0.08838834764831845f;           // fold C^-0.5 into the logits
    Mt[R * 128 + (t ^ ((R & 7) << 3))] = f2bf1(acc);
  } else {                                 // P row R
    const float* wv = w_qkv + 2 * 128 * 128;  // Wv[j][c]
    const float* wp = w_proj + (size_t)R * 128;  // Wproj[R][j]
    #pragma unroll 16
    for (int j = 0; j < 128; ++j)
      acc += wp[j] * wv[j * 128 + t];
    Pm[R * 128 + (t ^ ((R & 7) << 3))] = f2bf1(acc);
  }
}

// ---------------- Kernel 1: q' = x * Mt GEMM + bf16 transposed copy of x -----
// R8-verified combined form: 128-pixel tiles, only Xs in LDS (32 KB), Mt
// fragments direct from global, coalesced xq + qb stores.
__global__ __launch_bounds__(256) void k_qx(const float* __restrict__ x,
                                            const unsigned short* __restrict__ Mt,
                                            unsigned short* __restrict__ qb,
                                            unsigned* __restrict__ xq) {
  __shared__ __align__(16) unsigned short Xs[128 * 128];  // 32 KB
  const int t = threadIdx.x;
  const int gpix0 = blockIdx.x * 128;
  const int b = gpix0 >> 14;
  const int hw0 = gpix0 & (HW - 1);

  // stage Xs [pix][k] bf16, xor-swizzled
  const float* xb = x + (size_t)b * C * HW + hw0;
  #pragma unroll
  for (int i = 0; i < 16; ++i) {
    int linear = i * 256 + t;
    int p = linear & 127;
    int c4 = (linear >> 7) * 4;
    float a0 = xb[(size_t)(c4 + 0) * HW + p];
    float a1 = xb[(size_t)(c4 + 1) * HW + p];
    float a2 = xb[(size_t)(c4 + 2) * HW + p];
    float a3 = xb[(size_t)(c4 + 3) * HW + p];
    int cc = c4 ^ ((p & 7) << 3);
    *(uint2*)&Xs[p * 128 + cc] = make_uint2(pk2(a0, a1), pk2(a2, a3));
  }
  __syncthreads();

  // coalesced xq emit from staged Xs: [pix][64 dwords]
  #pragma unroll
  for (int i = 0; i < 8; ++i) {
    int linear = i * 256 + t;
    int c8 = (linear & 15) * 8;
    int prow = linear >> 4;
    uint4 v = *(const uint4*)&Xs[prow * 128 + (c8 ^ ((prow & 7) << 3))];
    *(uint4*)&xq[((size_t)(gpix0 + prow)) * 64 + (c8 >> 1)] = v;
  }

  const int wave = t >> 6, lane = t & 63;
  const int wr = wave >> 1, wc = wave & 1;
  const int rsel = lane & 15, quad = lane >> 4;

  f32x4 acc[4][4];
  #pragma unroll
  for (int mi = 0; mi < 4; ++mi)
    #pragma unroll
    for (int ni = 0; ni < 4; ++ni) acc[mi][ni] = (f32x4){0.f, 0.f, 0.f, 0.f};
  #pragma unroll
  for (int ks = 0; ks < 4; ++ks) {
    const int koff = ks * 32 + quad * 8;
    short8 afr[4], bfr[4];
    #pragma unroll
    for (int mi = 0; mi < 4; ++mi) {
      int r = wr * 64 + mi * 16 + rsel;
      afr[mi] = *(const short8*)&Xs[r * 128 + (koff ^ ((r & 7) << 3))];
    }
    #pragma unroll
    for (int ni = 0; ni < 4; ++ni) {
      int r = wc * 64 + ni * 16 + rsel;
      bfr[ni] = *(const short8*)&Mt[r * 128 + (koff ^ ((r & 7) << 3))];  // global, hot
    }
    #pragma unroll
    for (int mi = 0; mi < 4; ++mi)
      #pragma unroll
      for (int ni = 0; ni < 4; ++ni)
        acc[mi][ni] = __builtin_amdgcn_mfma_f32_16x16x32_bf16(afr[mi], bfr[ni], acc[mi][ni], 0, 0, 0);
  }
  __syncthreads();   // all Xs reads done; reuse Xs as q'-tile
  #pragma unroll
  for (int mi = 0; mi < 4; ++mi)
    #pragma unroll
    for (int ni = 0; ni < 4; ++ni)
      #pragma unroll
      for (int r = 0; r < 4; ++r) {
        int p = wr * 64 + mi * 16 + quad * 4 + r;
        int ch = wc * 64 + ni * 16 + rsel;
        Xs[p * 128 + (ch ^ ((p & 7) << 3))] = f2bf1(acc[mi][ni][r]);
      }
  __syncthreads();
  // coalesced qb store
  #pragma unroll
  for (int i = 0; i < 8; ++i) {
    int linear = i * 256 + t;
    int c8 = (linear & 15) * 8;
    int prow = linear >> 4;
    uint4 v = *(const uint4*)&Xs[prow * 128 + (c8 ^ ((prow & 7) << 3))];
    *(uint4*)(qb + (size_t)(gpix0 + prow) * C + c8) = v;
  }
}

// ---------------- Kernel 2: gather + attention + proj + residual -------------
// Gather/softmax phase is R9-verified (2 pix/wave, 32-bit voffset). Instead of
// storing o to global, o goes to a 4 KB LDS tile (16 rows, 8 valid); one
// barrier; then each wave computes a 32-och slice of out = x + P@o with 8
// MFMAs on the idle matrix pipe (Pm fragments from L2-hot global).
__global__ __launch_bounds__(256) void k_attn(const unsigned short* __restrict__ qb,
                                              const unsigned* __restrict__ xq,
                                              const int* __restrict__ psf,
                                              const int* __restrict__ pwu,
                                              const unsigned short* __restrict__ Pm,
                                              const float* __restrict__ x,
                                              float* __restrict__ out) {
  __shared__ __align__(16) unsigned short Ot[16 * 128];  // 4 KB (rows 8..15 zero)
  const int t = threadIdx.x;
  const int li = t & 31;
  const int half = (t >> 5) & 1;
  const int wave = t >> 6;
  const int gid = blockIdx.x;
  const int b = gid & 3;                         // batch -> XCD spread
  const int grp = gid >> 2;
  const int p0 = grp << 3;                       // block's 8-pixel base (in-batch)
  const int pixl = p0 + (wave << 1) + half;      // per-lane pixel
  const size_t spix = ((size_t)b << 14) + pixl;

  // zero the pad rows 8..15 of Ot (covered by the pre-proj barrier)
  ((uint2*)(Ot + 8 * 128))[t] = make_uint2(0u, 0u);

  // scalar tables: pw[0..15], pw[16..31], pi[0..15] (contiguous in workspace)
  v16i w0, w1, tpi;
  asm volatile(
      "s_load_dwordx16 %0, %3, 0\n\t"
      "s_load_dwordx16 %1, %3, 64\n\t"
      "s_load_dwordx16 %2, %3, 128\n\t"
      "s_waitcnt lgkmcnt(0)"
      : "=&s"(w0), "=&s"(w1), "=&s"(tpi)
      : "s"(pwu));

  // per-lane anchor row (uniform within each 32-lane half -> broadcast)
  const int4* pr = (const int4*)(psf + spix * 16);
  int4 a0 = pr[0], a1 = pr[1], a2 = pr[2], a3 = pr[3];
  int va[16] = {a0.x, a0.y, a0.z, a0.w, a1.x, a1.y, a1.z, a1.w,
                a2.x, a2.y, a2.z, a2.w, a3.x, a3.y, a3.z, a3.w};

  // q for my 4 channels
  const uint2 qp = *(const uint2*)((const unsigned*)qb + spix * 64 + 2 * li);
  const float q0 = bflo(qp.x), q1 = bfhi(qp.x);
  const float q2 = bflo(qp.y), q3 = bfhi(qp.y);

  const unsigned* xB = xq + (((size_t)b << 14) << 6);  // batch base (dwords)

  float s0[8], s1[8], s2[8], s3[8], dk[8];
  #pragma unroll
  for (int k = 0; k < 8; ++k) {
    const int x0 = va[2 * k + 0] + tpi[2 * k + 0];
    const int y0 = va[2 * k + 1] + tpi[2 * k + 1];
    float t0 = 0.f, t1 = 0.f, t2 = 0.f, t3 = 0.f;
    #pragma unroll
    for (int cn = 0; cn < 4; ++cn) {
      const int xi = x0 + (cn & 1);
      const int yi = y0 + (cn >> 1);
      const bool valid = ((unsigned)xi <= 127u) & ((unsigned)yi <= 127u);
      const int xc = min(max(xi, 0), 127);   // v_med3_i32
      const int yc = min(max(yi, 0), 127);
      const int widx = k * 4 + cn;
      const float wv = valid ? asf(widx < 16 ? w0[widx & 15] : w1[widx & 15]) : 0.0f;
      const unsigned off = (((unsigned)((yc << 7) + xc)) << 6) + 2u * (unsigned)li;
      const uint2 w2 = *(const uint2*)&xB[off];      // 32-bit voffset
      t0 = fmaf(bflo(w2.x), wv, t0); t1 = fmaf(bfhi(w2.x), wv, t1);
      t2 = fmaf(bflo(w2.y), wv, t2); t3 = fmaf(bfhi(w2.y), wv, t3);
    }
    s0[k] = t0; s1[k] = t1; s2[k] = t2; s3[k] = t3;
    dk[k] = fmaf(q0, t0, fmaf(q1, t1, fmaf(q2, t2, q3 * t3)));
  }
  #pragma unroll
  for (int off = 16; off > 0; off >>= 1) {
    #pragma unroll
    for (int k = 0; k < 8; ++k) dk[k] += __shfl_xor(dk[k], off);
  }
  float m = dk[0];
  #pragma unroll
  for (int k = 1; k < 8; ++k) m = fmaxf(m, dk[k]);
  float den = 0.0f;
  #pragma unroll
  for (int k = 0; k < 8; ++k) { dk[k] = __expf(dk[k] - m); den += dk[k]; }
  const float inv = 1.0f / den;
  float o0 = 0.f, o1 = 0.f, o2 = 0.f, o3 = 0.f;
  #pragma unroll
  for (int k = 0; k < 8; ++k) {
    const float pk = dk[k] * inv;
    o0 = fmaf(pk, s0[k], o0); o1 = fmaf(pk, s1[k], o1);
    o2 = fmaf(pk, s2[k], o2); o3 = fmaf(pk, s3[k], o3);
  }
  // o -> LDS (bf16, swizzled row = local pixel 0..7)
  const int prow = (wave << 1) + half;
  *(uint2*)&Ot[prow * 128 + ((4 * li) ^ ((prow & 7) << 3))] =
      make_uint2(pk2(o0, o1), pk2(o2, o3));
  __syncthreads();

  // proj phase: wave computes och slice [wave*32, wave*32+32) for 8 pixels
  {
    const int rsel = t & 15, quad = (t >> 4) & 3;
    f32x4 pa0 = (f32x4){0.f, 0.f, 0.f, 0.f};
    f32x4 pa1 = (f32x4){0.f, 0.f, 0.f, 0.f};
    #pragma unroll
    for (int ks = 0; ks < 4; ++ks) {
      const int koff = ks * 32 + quad * 8;
      short8 bfr = *(const short8*)&Ot[rsel * 128 + (koff ^ ((rsel & 7) << 3))];
      int r0 = wave * 32 + rsel;
      short8 af0 = *(const short8*)&Pm[r0 * 128 + (koff ^ ((r0 & 7) << 3))];
      int r1 = wave * 32 + 16 + rsel;
      short8 af1 = *(const short8*)&Pm[r1 * 128 + (koff ^ ((r1 & 7) << 3))];
      pa0 = __builtin_amdgcn_mfma_f32_16x16x32_bf16(af0, bfr, pa0, 0, 0, 0);
      pa1 = __builtin_amdgcn_mfma_f32_16x16x32_bf16(af1, bfr, pa1, 0, 0, 0);
    }
    if (rsel < 8) {
      #pragma unroll
      for (int r = 0; r < 4; ++r) {
        int och0 = wave * 32 + quad * 4 + r;
        size_t ad0 = ((size_t)b * C + och0) * HW + p0 + rsel;
        out[ad0] = x[ad0] + pa0[r];
        int och1 = och0 + 16;
        size_t ad1 = ((size_t)b * C + och1) * HW + p0 + rsel;
        out[ad1] = x[ad1] + pa1[r];
      }
    }
  }
}

extern "C" void kernel_launch(void* const* d_in, const int* in_sizes, int n_in,
                              void* d_out, int out_size, void* d_ws, size_t ws_size,
                              hipStream_t stream) {
  const float* x      = (const float*)d_in[0];
  const int*   psf    = (const int*)d_in[1];
  const float* delta  = (const float*)d_in[2];
  const float* w_qkv  = (const float*)d_in[3];
  const float* w_proj = (const float*)d_in[4];
  float* out = (float*)d_out;

  const size_t N = (size_t)4 * HW * C;                 // 8388608 elems
  unsigned short* qb = (unsigned short*)d_ws;          // 16 MB bf16 q' [pix][ch]
  unsigned short* xq = qb + N;                         // 16 MB bf16 x~ [pix][ch]
  unsigned short* Mt = xq + N;                         // 32 KB bf16 swz
  unsigned short* Pm = Mt + 16384;                     // 32 KB bf16 swz
  float* pw = (float*)(Pm + 16384);                    // 32 floats (pi follows)
  int*   pi = (int*)(pw + 32);                         // 16 ints
  (void)pi;

  k_prep<<<dim3(257), 128, 0, stream>>>(w_qkv, w_proj, delta, Mt, Pm, pw, pi);
  k_qx<<<dim3(512), 256, 0, stream>>>(x, Mt, qb, (unsigned*)xq);
  k_attn<<<dim3(8192), 256, 0, stream>>>(qb, (const unsigned*)xq, psf, (const int*)pw,
                                         Pm, x, out);
}

// Round 11
// 164.091 us; speedup vs baseline: 1.0098x; 1.0098x over previous
//
#include <hip/hip_runtime.h>

#define HW 16384
#define C 128

typedef __attribute__((ext_vector_type(8))) short short8;
typedef __attribute__((ext_vector_type(4))) float f32x4;
typedef __attribute__((ext_vector_type(2))) float f32x2;
typedef __attribute__((ext_vector_type(16))) int v16i;

__device__ __forceinline__ unsigned short f2bf(float f) {
  union { float f; unsigned u; } v; v.f = f;
  return (unsigned short)((v.u + 0x7fffu + ((v.u >> 16) & 1u)) >> 16);
}
#if __has_builtin(__builtin_amdgcn_cvt_pk_bf16_f32)
typedef __attribute__((ext_vector_type(2))) __bf16 bf16x2;
__device__ __forceinline__ unsigned pk2(float a, float b) {   // HW RNE pack
  union { bf16x2 v; unsigned u; } cv;
  cv.v = __builtin_amdgcn_cvt_pk_bf16_f32(a, b);
  return cv.u;
}
#else
__device__ __forceinline__ unsigned pk2(float a, float b) {   // SW RNE pack
  return (unsigned)f2bf(a) | ((unsigned)f2bf(b) << 16);
}
#endif
__device__ __forceinline__ unsigned short f2bf1(float a) {
  return (unsigned short)(pk2(a, a) & 0xffffu);
}
__device__ __forceinline__ float bflo(unsigned w) {
  union { unsigned u; float f; } v; v.u = w << 16; return v.f;
}
__device__ __forceinline__ float bfhi(unsigned w) {
  union { unsigned u; float f; } v; v.u = w & 0xffff0000u; return v.f;
}
__device__ __forceinline__ float asf(int u) {
  union { int u; float f; } v; v.u = u; return v.f;
}

// ---------------- Kernel 0: precompute Mt = C^-0.5 * Wk^T Wq, P = Wproj @ Wv,
// both stored bf16 with the fragment XOR swizzle pre-applied, plus pw/pi.
__global__ __launch_bounds__(128) void k_prep(const float* __restrict__ w_qkv,
                                              const float* __restrict__ w_proj,
                                              const float* __restrict__ delta,
                                              unsigned short* __restrict__ Mt,
                                              unsigned short* __restrict__ Pm,
                                              float* __restrict__ pw,
                                              int* __restrict__ pi) {
  const int bid = blockIdx.x;
  const int t = threadIdx.x;
  if (bid == 256) {
    if (t < 8) {
      float s0 = tanhf(delta[t * 2 + 0]) * 4.0f;  // col shift (x)
      float s1 = tanhf(delta[t * 2 + 1]) * 4.0f;  // row shift (y)
      float f0 = floorf(s0), f1 = floorf(s1);
      pi[2 * t + 0] = (int)f0;
      pi[2 * t + 1] = (int)f1;
      float fx = s0 - f0, fy = s1 - f1;
      pw[4 * t + 0] = (1.0f - fx) * (1.0f - fy);
      pw[4 * t + 1] = fx * (1.0f - fy);
      pw[4 * t + 2] = (1.0f - fx) * fy;
      pw[4 * t + 3] = fx * fy;
    }
    return;
  }
  const int R = bid & 127;
  float acc = 0.0f;
  if (bid < 128) {                         // Mt row R
    const float* wq = w_qkv;               // Wq[j][c]
    const float* wk = w_qkv + 128 * 128;   // Wk[j][o]
    #pragma unroll 16
    for (int j = 0; j < 128; ++j)
      acc += wk[j * 128 + R] * wq[j * 128 + t];   // wk: scalar, wq: coalesced
    acc *= 0.08838834764831845f;           // fold C^-0.5 into the logits
    Mt[R * 128 + (t ^ ((R & 7) << 3))] = f2bf1(acc);
  } else {                                 // P row R
    const float* wv = w_qkv + 2 * 128 * 128;  // Wv[j][c]
    const float* wp = w_proj + (size_t)R * 128;  // Wproj[R][j]
    #pragma unroll 16
    for (int j = 0; j < 128; ++j)
      acc += wp[j] * wv[j * 128 + t];
    Pm[R * 128 + (t ^ ((R & 7) << 3))] = f2bf1(acc);
  }
}

// ---------------- Kernel 1: q' = x * Mt GEMM + bf16 transposed copy of x -----
// R8-verified combined form: 128-pixel tiles, only Xs in LDS (32 KB), Mt
// fragments direct from global, coalesced xq + qb stores.
__global__ __launch_bounds__(256) void k_qx(const float* __restrict__ x,
                                            const unsigned short* __restrict__ Mt,
                                            unsigned short* __restrict__ qb,
                                            unsigned* __restrict__ xq) {
  __shared__ __align__(16) unsigned short Xs[128 * 128];  // 32 KB
  const int t = threadIdx.x;
  const int gpix0 = blockIdx.x * 128;
  const int b = gpix0 >> 14;
  const int hw0 = gpix0 & (HW - 1);

  // stage Xs [pix][k] bf16, xor-swizzled
  const float* xb = x + (size_t)b * C * HW + hw0;
  #pragma unroll
  for (int i = 0; i < 16; ++i) {
    int linear = i * 256 + t;
    int p = linear & 127;
    int c4 = (linear >> 7) * 4;
    float a0 = xb[(size_t)(c4 + 0) * HW + p];
    float a1 = xb[(size_t)(c4 + 1) * HW + p];
    float a2 = xb[(size_t)(c4 + 2) * HW + p];
    float a3 = xb[(size_t)(c4 + 3) * HW + p];
    int cc = c4 ^ ((p & 7) << 3);
    *(uint2*)&Xs[p * 128 + cc] = make_uint2(pk2(a0, a1), pk2(a2, a3));
  }
  __syncthreads();

  // coalesced xq emit from staged Xs: [pix][64 dwords]
  #pragma unroll
  for (int i = 0; i < 8; ++i) {
    int linear = i * 256 + t;
    int c8 = (linear & 15) * 8;
    int prow = linear >> 4;
    uint4 v = *(const uint4*)&Xs[prow * 128 + (c8 ^ ((prow & 7) << 3))];
    *(uint4*)&xq[((size_t)(gpix0 + prow)) * 64 + (c8 >> 1)] = v;
  }

  const int wave = t >> 6, lane = t & 63;
  const int wr = wave >> 1, wc = wave & 1;
  const int rsel = lane & 15, quad = lane >> 4;

  f32x4 acc[4][4];
  #pragma unroll
  for (int mi = 0; mi < 4; ++mi)
    #pragma unroll
    for (int ni = 0; ni < 4; ++ni) acc[mi][ni] = (f32x4){0.f, 0.f, 0.f, 0.f};
  #pragma unroll
  for (int ks = 0; ks < 4; ++ks) {
    const int koff = ks * 32 + quad * 8;
    short8 afr[4], bfr[4];
    #pragma unroll
    for (int mi = 0; mi < 4; ++mi) {
      int r = wr * 64 + mi * 16 + rsel;
      afr[mi] = *(const short8*)&Xs[r * 128 + (koff ^ ((r & 7) << 3))];
    }
    #pragma unroll
    for (int ni = 0; ni < 4; ++ni) {
      int r = wc * 64 + ni * 16 + rsel;
      bfr[ni] = *(const short8*)&Mt[r * 128 + (koff ^ ((r & 7) << 3))];  // global, hot
    }
    #pragma unroll
    for (int mi = 0; mi < 4; ++mi)
      #pragma unroll
      for (int ni = 0; ni < 4; ++ni)
        acc[mi][ni] = __builtin_amdgcn_mfma_f32_16x16x32_bf16(afr[mi], bfr[ni], acc[mi][ni], 0, 0, 0);
  }
  __syncthreads();   // all Xs reads done; reuse Xs as q'-tile
  #pragma unroll
  for (int mi = 0; mi < 4; ++mi)
    #pragma unroll
    for (int ni = 0; ni < 4; ++ni)
      #pragma unroll
      for (int r = 0; r < 4; ++r) {
        int p = wr * 64 + mi * 16 + quad * 4 + r;
        int ch = wc * 64 + ni * 16 + rsel;
        Xs[p * 128 + (ch ^ ((p & 7) << 3))] = f2bf1(acc[mi][ni][r]);
      }
  __syncthreads();
  // coalesced qb store
  #pragma unroll
  for (int i = 0; i < 8; ++i) {
    int linear = i * 256 + t;
    int c8 = (linear & 15) * 8;
    int prow = linear >> 4;
    uint4 v = *(const uint4*)&Xs[prow * 128 + (c8 ^ ((prow & 7) << 3))];
    *(uint4*)(qb + (size_t)(gpix0 + prow) * C + c8) = v;
  }
}

// ---------------- Kernel 2: gather + attention + proj + residual -------------
// 32 pixels per 1024-thread block (16 waves, grid 2048). Gather/softmax is the
// R9-verified per-wave code (2 pix/wave). o -> 8 KB LDS tile (32 rows, all
// valid); one barrier; each wave then computes one 16-och x 16-pix tile of
// out = x + P@o (4 MFMAs, single f32x4 acc). out/x cache lines (32 pix = 128 B)
// are fully covered by the block -> no RMW overfetch (R10's failure mode).
__global__ __launch_bounds__(1024) void k_attn(const unsigned short* __restrict__ qb,
                                               const unsigned* __restrict__ xq,
                                               const int* __restrict__ psf,
                                               const int* __restrict__ pwu,
                                               const unsigned short* __restrict__ Pm,
                                               const float* __restrict__ x,
                                               float* __restrict__ out) {
  __shared__ __align__(16) unsigned short Ot[32 * 128];  // 8 KB
  const int t = threadIdx.x;
  const int li = t & 31;
  const int half = (t >> 5) & 1;
  const int wave = t >> 6;                       // 0..15
  const int gid = blockIdx.x;
  const int b = gid & 3;                         // batch -> XCD spread
  const int grp = gid >> 2;
  const int p0 = grp << 5;                       // block's 32-pixel base (in-batch)
  const int pixl = p0 + (wave << 1) + half;      // per-lane pixel
  const size_t spix = ((size_t)b << 14) + pixl;

  // scalar tables: pw[0..15], pw[16..31], pi[0..15] (contiguous in workspace)
  v16i w0, w1, tpi;
  asm volatile(
      "s_load_dwordx16 %0, %3, 0\n\t"
      "s_load_dwordx16 %1, %3, 64\n\t"
      "s_load_dwordx16 %2, %3, 128\n\t"
      "s_waitcnt lgkmcnt(0)"
      : "=&s"(w0), "=&s"(w1), "=&s"(tpi)
      : "s"(pwu));

  // per-lane anchor row (uniform within each 32-lane half -> broadcast)
  const int4* pr = (const int4*)(psf + spix * 16);
  int4 a0 = pr[0], a1 = pr[1], a2 = pr[2], a3 = pr[3];
  int va[16] = {a0.x, a0.y, a0.z, a0.w, a1.x, a1.y, a1.z, a1.w,
                a2.x, a2.y, a2.z, a2.w, a3.x, a3.y, a3.z, a3.w};

  // q for my 4 channels
  const uint2 qp = *(const uint2*)((const unsigned*)qb + spix * 64 + 2 * li);
  const float q0 = bflo(qp.x), q1 = bfhi(qp.x);
  const float q2 = bflo(qp.y), q3 = bfhi(qp.y);

  const unsigned* xB = xq + (((size_t)b << 14) << 6);  // batch base (dwords)

  float s0[8], s1[8], s2[8], s3[8], dk[8];
  #pragma unroll
  for (int k = 0; k < 8; ++k) {
    const int x0 = va[2 * k + 0] + tpi[2 * k + 0];
    const int y0 = va[2 * k + 1] + tpi[2 * k + 1];
    float t0 = 0.f, t1 = 0.f, t2 = 0.f, t3 = 0.f;
    #pragma unroll
    for (int cn = 0; cn < 4; ++cn) {
      const int xi = x0 + (cn & 1);
      const int yi = y0 + (cn >> 1);
      const bool valid = ((unsigned)xi <= 127u) & ((unsigned)yi <= 127u);
      const int xc = min(max(xi, 0), 127);   // v_med3_i32
      const int yc = min(max(yi, 0), 127);
      const int widx = k * 4 + cn;
      const float wv = valid ? asf(widx < 16 ? w0[widx & 15] : w1[widx & 15]) : 0.0f;
      const unsigned off = (((unsigned)((yc << 7) + xc)) << 6) + 2u * (unsigned)li;
      const uint2 w2 = *(const uint2*)&xB[off];      // 32-bit voffset
      t0 = fmaf(bflo(w2.x), wv, t0); t1 = fmaf(bfhi(w2.x), wv, t1);
      t2 = fmaf(bflo(w2.y), wv, t2); t3 = fmaf(bfhi(w2.y), wv, t3);
    }
    s0[k] = t0; s1[k] = t1; s2[k] = t2; s3[k] = t3;
    dk[k] = fmaf(q0, t0, fmaf(q1, t1, fmaf(q2, t2, q3 * t3)));
  }
  #pragma unroll
  for (int off = 16; off > 0; off >>= 1) {
    #pragma unroll
    for (int k = 0; k < 8; ++k) dk[k] += __shfl_xor(dk[k], off);
  }
  float m = dk[0];
  #pragma unroll
  for (int k = 1; k < 8; ++k) m = fmaxf(m, dk[k]);
  float den = 0.0f;
  #pragma unroll
  for (int k = 0; k < 8; ++k) { dk[k] = __expf(dk[k] - m); den += dk[k]; }
  const float inv = 1.0f / den;
  float o0 = 0.f, o1 = 0.f, o2 = 0.f, o3 = 0.f;
  #pragma unroll
  for (int k = 0; k < 8; ++k) {
    const float pk = dk[k] * inv;
    o0 = fmaf(pk, s0[k], o0); o1 = fmaf(pk, s1[k], o1);
    o2 = fmaf(pk, s2[k], o2); o3 = fmaf(pk, s3[k], o3);
  }
  // o -> LDS (bf16, swizzled row = local pixel 0..31)
  const int prow = (wave << 1) + half;
  *(uint2*)&Ot[prow * 128 + ((4 * li) ^ ((prow & 7) << 3))] =
      make_uint2(pk2(o0, o1), pk2(o2, o3));
  __syncthreads();

  // proj phase: wave -> 16-och x 16-pix tile; och block (wave&7)*16,
  // pix block (wave>>3)*16. A = Pm och-rows, B = Ot pix-rows.
  {
    const int rsel = t & 15, quad = (t >> 4) & 3;
    const int ochb = (wave & 7) << 4;
    const int pc = (wave >> 3) << 4;
    f32x4 pa = (f32x4){0.f, 0.f, 0.f, 0.f};
    #pragma unroll
    for (int ks = 0; ks < 4; ++ks) {
      const int koff = ks * 32 + quad * 8;
      const int br = pc + rsel;
      short8 bfr = *(const short8*)&Ot[br * 128 + (koff ^ ((br & 7) << 3))];
      const int ar = ochb + rsel;
      short8 afr = *(const short8*)&Pm[ar * 128 + (koff ^ ((ar & 7) << 3))];
      pa = __builtin_amdgcn_mfma_f32_16x16x32_bf16(afr, bfr, pa, 0, 0, 0);
    }
    #pragma unroll
    for (int r = 0; r < 4; ++r) {
      const int och = ochb + quad * 4 + r;
      const size_t ad = ((size_t)b * C + och) * HW + p0 + pc + rsel;
      out[ad] = x[ad] + pa[r];
    }
  }
}

extern "C" void kernel_launch(void* const* d_in, const int* in_sizes, int n_in,
                              void* d_out, int out_size, void* d_ws, size_t ws_size,
                              hipStream_t stream) {
  const float* x      = (const float*)d_in[0];
  const int*   psf    = (const int*)d_in[1];
  const float* delta  = (const float*)d_in[2];
  const float* w_qkv  = (const float*)d_in[3];
  const float* w_proj = (const float*)d_in[4];
  float* out = (float*)d_out;

  const size_t N = (size_t)4 * HW * C;                 // 8388608 elems
  unsigned short* qb = (unsigned short*)d_ws;          // 16 MB bf16 q' [pix][ch]
  unsigned short* xq = qb + N;                         // 16 MB bf16 x~ [pix][ch]
  unsigned short* Mt = xq + N;                         // 32 KB bf16 swz
  unsigned short* Pm = Mt + 16384;                     // 32 KB bf16 swz
  float* pw = (float*)(Pm + 16384);                    // 32 floats (pi follows)
  int*   pi = (int*)(pw + 32);                         // 16 ints
  (void)pi;

  k_prep<<<dim3(257), 128, 0, stream>>>(w_qkv, w_proj, delta, Mt, Pm, pw, pi);
  k_qx<<<dim3(512), 256, 0, stream>>>(x, Mt, qb, (unsigned*)xq);
  k_attn<<<dim3(2048), 1024, 0, stream>>>(qb, (const unsigned*)xq, psf, (const int*)pw,
                                          Pm, x, out);
}